// Round 10
// baseline (3210.689 us; speedup 1.0000x reference)
//
#include <hip/hip_runtime.h>
#include <hip/hip_bf16.h>

// Problem dims
#define Bb 256
#define Tt 256
#define Dd 512
#define Hh 1024
#define Cc 1000

typedef short  bf16x8 __attribute__((ext_vector_type(8)));
typedef float  f32x4  __attribute__((ext_vector_type(4)));
typedef unsigned short u16x8 __attribute__((ext_vector_type(8)));

// 32-k chunks for MFMA 16x16x32. Per 16-col block:
//  z : 16 x-chunks [0,16) + 32 h-chunks [16,48)
//  r : 16 x-chunks [48,64) + 32 h-chunks [64,96)
//  xh: 16 x-chunks [96,112)
//  hU: 32 h-chunks [112,144)
#define NCI 144
// packed: [cblk(64)][ci(144)][lane(64)][8 elems] bf16 = 9,437,184 B

__device__ __forceinline__ unsigned short f2bf(float f) {
  unsigned u = __float_as_uint(f);
  u += 0x7FFFu + ((u >> 16) & 1u);       // RNE
  return (unsigned short)(u >> 16);
}

// ---------------- pack weights into MFMA-fragment order (bf16) ----------------
// B-fragment for 16x16x32: col = lane&15, k = (lane>>4)*8 + e
__global__ void pack_weights(const float* __restrict__ Wz, const float* __restrict__ Wr,
                             const float* __restrict__ W,  const float* __restrict__ Uz,
                             const float* __restrict__ Ur, const float* __restrict__ U,
                             unsigned short* __restrict__ packed) {
  int tid = blockIdx.x * 256 + threadIdx.x;           // one thread = one (c,ci,lane) -> 8 elems
  if (tid >= 64 * NCI * 64) return;
  int lane = tid & 63;
  int rest = tid >> 6;
  int ci   = rest % NCI;
  int c    = rest / NCI;                               // 0..63 col block
  int j    = (c << 4) + (lane & 15);                   // output column
  int kg   = lane >> 4;                                // 0..3
  const float* src; int kb;
  if      (ci < 16)  { src = Wz; kb = ci*32; }
  else if (ci < 48)  { src = Uz; kb = (ci-16)*32; }
  else if (ci < 64)  { src = Wr; kb = (ci-48)*32; }
  else if (ci < 96)  { src = Ur; kb = (ci-64)*32; }
  else if (ci < 112) { src = W;  kb = (ci-96)*32; }
  else               { src = U;  kb = (ci-112)*32; }
  int k0 = kb + kg*8;
  u16x8 o;
  #pragma unroll
  for (int e = 0; e < 8; ++e) o[e] = f2bf(src[(size_t)(k0+e)*Hh + j]);
  *(u16x8*)(packed + (size_t)tid*8) = o;
}

// ---------------- x fp32 -> bf16 (optional, if ws is big enough) ----------------
__global__ void cvt_x(const float* __restrict__ x, unsigned short* __restrict__ xb) {
  const int n4 = (Bb*Tt*Dd)/4;
  for (int i = blockIdx.x*256 + threadIdx.x; i < n4; i += gridDim.x*256) {
    f32x4 v = *(const f32x4*)(x + (size_t)i*4);
    unsigned short o[4];
    #pragma unroll
    for (int e = 0; e < 4; ++e) o[e] = f2bf(v[e]);
    *(unsigned long long*)(xb + (size_t)i*4) = *(unsigned long long*)o;
  }
}

// ---------------- one GRU timestep ----------------
// Launched 256x inside the captured graph (kernel boundary = HW-amortized
// cross-XCD coherence — R9-proven). grid = 256 WGs (4 rblk x 64 cblk),
// 256 threads (4 waves x 16 rows). R10 change: weight staging via
// global_load_lds width=16 (fire-and-forget DMA, no VGPR round trip) so the
// ha/hold/xa latency overlaps the staging instead of stacking behind it.
template<bool T0, bool XBF>
__global__ void __launch_bounds__(256, 1)
gru_step(const float* __restrict__ x, const unsigned short* __restrict__ xb,
         const unsigned short* __restrict__ packed,
         const unsigned short* __restrict__ hbsrc, unsigned short* __restrict__ hbdst,
         const float* __restrict__ hfsrc, float* __restrict__ hfdst,
         int t) {
  __shared__ short lds[NCI * 512];                     // 147,456 B weight slice

  const int wg   = blockIdx.x;
  const int cblk = wg & 63;
  const int rblk = wg >> 6;
  const int tid  = threadIdx.x;
  const int lane = tid & 63;
  const int wave = tid >> 6;

  const int arow = lane & 15;                  // A row within wave's 16-row tile
  const int kg   = lane >> 4;                  // k-group 0..3 (k = kg*8 + e)
  const int b    = rblk*64 + wave*16 + arow;   // A-operand batch row
  const int crow = rblk*64 + wave*16 + kg*4;   // C/D row base (+e)
  const int j    = (cblk << 4) + arow;         // C/D column

  // ---- stage weight slice via async DMA: 36 x global_load_lds_dwordx4 ----
  // LDS dest = wave-uniform base + lane*16 (linear layout, matches reads below)
  {
    const unsigned short* gsrc = packed + (size_t)cblk * (NCI * 512);
    #pragma unroll
    for (int i = 0; i < 36; ++i) {
      const unsigned short* g = gsrc + (size_t)(i*256 + wave*64 + lane) * 8;
      short* l = lds + (size_t)(i*256 + wave*64) * 8;
      __builtin_amdgcn_global_load_lds(
          (const __attribute__((address_space(1))) unsigned*)g,
          (__attribute__((address_space(3))) unsigned*)l, 16, 0, 0);
    }
  }

  // ---- h A-fragments + fp32 master (overlap the staging DMA) ----
  bf16x8 ha[32];
  float  hold[4];
  if constexpr (!T0) {
    const unsigned short* hrow = hbsrc + (size_t)b * Hh;
    #pragma unroll
    for (int kk = 0; kk < 32; ++kk) ha[kk] = *(const bf16x8*)(hrow + kk*32 + kg*8);
    #pragma unroll
    for (int e = 0; e < 4; ++e) hold[e] = hfsrc[(size_t)(crow+e)*Hh + j];
  } else {
    #pragma unroll
    for (int e = 0; e < 4; ++e) hold[e] = 0.f;
  }

  // ---- x A-fragments ----
  bf16x8 xa[16];
  if constexpr (XBF) {
    const unsigned short* xt = xb + ((size_t)b * Tt + t) * Dd;
    #pragma unroll
    for (int kk = 0; kk < 16; ++kk) xa[kk] = *(const bf16x8*)(xt + kk*32 + kg*8);
  } else {
    const float* xt = x + ((size_t)b * Tt + t) * Dd;
    #pragma unroll
    for (int kk = 0; kk < 16; ++kk) {
      f32x4 v0 = *(const f32x4*)(xt + kk*32 + kg*8);
      f32x4 v1 = *(const f32x4*)(xt + kk*32 + kg*8 + 4);
      bf16x8 a;
      #pragma unroll
      for (int e = 0; e < 4; ++e) { ((unsigned short*)&a)[e] = f2bf(v0[e]); ((unsigned short*)&a)[e+4] = f2bf(v1[e]); }
      xa[kk] = a;
    }
  }

  __syncthreads();                                     // drains vmcnt (DMA + loads)

  f32x4 az  = {0.f,0.f,0.f,0.f};
  f32x4 arr = {0.f,0.f,0.f,0.f};
  f32x4 axh = {0.f,0.f,0.f,0.f};
  f32x4 ahu = {0.f,0.f,0.f,0.f};

  // x-part
  #pragma unroll
  for (int kk = 0; kk < 16; ++kk) {
    bf16x8 bz = *(const bf16x8*)&lds[(0  + kk)*512 + lane*8];
    bf16x8 br = *(const bf16x8*)&lds[(48 + kk)*512 + lane*8];
    bf16x8 bx = *(const bf16x8*)&lds[(96 + kk)*512 + lane*8];
    az  = __builtin_amdgcn_mfma_f32_16x16x32_bf16(xa[kk], bz, az , 0,0,0);
    arr = __builtin_amdgcn_mfma_f32_16x16x32_bf16(xa[kk], br, arr, 0,0,0);
    axh = __builtin_amdgcn_mfma_f32_16x16x32_bf16(xa[kk], bx, axh, 0,0,0);
  }
  // h-part
  if constexpr (!T0) {
    #pragma unroll
    for (int kk = 0; kk < 32; ++kk) {
      bf16x8 bz = *(const bf16x8*)&lds[(16  + kk)*512 + lane*8];
      bf16x8 br = *(const bf16x8*)&lds[(64  + kk)*512 + lane*8];
      bf16x8 bu = *(const bf16x8*)&lds[(112 + kk)*512 + lane*8];
      az  = __builtin_amdgcn_mfma_f32_16x16x32_bf16(ha[kk], bz, az , 0,0,0);
      arr = __builtin_amdgcn_mfma_f32_16x16x32_bf16(ha[kk], br, arr, 0,0,0);
      ahu = __builtin_amdgcn_mfma_f32_16x16x32_bf16(ha[kk], bu, ahu, 0,0,0);
    }
  }

  // ---- gate epilogue: h_new = z*h + (1-z)*tanh(xh + (hU)*r) ----
  #pragma unroll
  for (int e = 0; e < 4; ++e) {
    float z  = 1.f / (1.f + __expf(-az[e]));
    float r  = 1.f / (1.f + __expf(-arr[e]));
    float u  = axh[e] + ahu[e] * r;
    float hh = 2.f / (1.f + __expf(-2.f * u)) - 1.f;    // tanh
    float hn = z*hold[e] + (1.f - z)*hh;
    hfdst[(size_t)(crow+e)*Hh + j] = hn;                // fp32 master
    hbdst[(size_t)(crow+e)*Hh + j] = f2bf(hn);          // bf16 operand copy
  }
}

// ---------------- classifier: p = h_last @ W_ph + b_p ----------------
__global__ void classifier(const float* __restrict__ h, const float* __restrict__ Wph,
                           const float* __restrict__ bp, float* __restrict__ out) {
  __shared__ float hsm[8 * Hh];                 // transposed: [k][r]
  const int cb = blockIdx.x, bbk = blockIdx.y;
  const int tid = threadIdx.x;
  const float* h0 = h + (size_t)bbk * 8 * Hh;
  for (int i = tid; i < 8 * Hh; i += 256) {
    int r = i >> 10, k = i & (Hh - 1);
    hsm[k*8 + r] = h0[i];
  }
  __syncthreads();
  int c = cb*256 + tid;
  bool act = c < Cc;
  float acc[8] = {0,0,0,0,0,0,0,0};
  for (int k = 0; k < Hh; ++k) {
    float w = act ? Wph[(size_t)k*Cc + c] : 0.f;
    f32x4 h0v = *(const f32x4*)&hsm[k*8];
    f32x4 h1v = *(const f32x4*)&hsm[k*8 + 4];
    acc[0] += h0v[0]*w; acc[1] += h0v[1]*w; acc[2] += h0v[2]*w; acc[3] += h0v[3]*w;
    acc[4] += h1v[0]*w; acc[5] += h1v[1]*w; acc[6] += h1v[2]*w; acc[7] += h1v[3]*w;
  }
  if (act) {
    float bias = bp[c];
    #pragma unroll
    for (int r = 0; r < 8; ++r) out[(size_t)(bbk*8 + r)*Cc + c] = acc[r] + bias;
  }
}

// ---------------- in-place log_softmax over rows of [256,1000] ----------------
__global__ void logsoftmax(float* __restrict__ out) {
  __shared__ float sm[4];
  float* row = out + (size_t)blockIdx.x * Cc;
  const int tid = threadIdx.x;
  float m = -3.4e38f;
  for (int i = tid; i < Cc; i += 256) m = fmaxf(m, row[i]);
  #pragma unroll
  for (int o = 32; o; o >>= 1) m = fmaxf(m, __shfl_down(m, o, 64));
  if ((tid & 63) == 0) sm[tid >> 6] = m;
  __syncthreads();
  m = fmaxf(fmaxf(sm[0], sm[1]), fmaxf(sm[2], sm[3]));
  __syncthreads();
  float s = 0.f;
  for (int i = tid; i < Cc; i += 256) s += __expf(row[i] - m);
  #pragma unroll
  for (int o = 32; o; o >>= 1) s += __shfl_down(s, o, 64);
  if ((tid & 63) == 0) sm[tid >> 6] = s;
  __syncthreads();
  s = sm[0] + sm[1] + sm[2] + sm[3];
  float lse = m + __logf(s);
  for (int i = tid; i < Cc; i += 256) row[i] -= lse;
}

extern "C" void kernel_launch(void* const* d_in, const int* in_sizes, int n_in,
                              void* d_out, int out_size, void* d_ws, size_t ws_size,
                              hipStream_t stream) {
  (void)in_sizes; (void)n_in; (void)out_size;
  const float* x   = (const float*)d_in[0];
  const float* Wz  = (const float*)d_in[1];
  const float* Wr  = (const float*)d_in[2];
  const float* W   = (const float*)d_in[3];
  const float* Uz  = (const float*)d_in[4];
  const float* Ur  = (const float*)d_in[5];
  const float* U   = (const float*)d_in[6];
  const float* Wph = (const float*)d_in[7];
  const float* bp  = (const float*)d_in[8];
  float* out = (float*)d_out;

  char* ws = (char*)d_ws;
  const size_t OFF_PACK = 0;                       // 9,437,184 B
  const size_t OFF_HB   = 9437184;                 // 1,048,576 B (2 x [256,1024] bf16)
  const size_t OFF_HF   = OFF_HB + 1048576;        // 2,097,152 B (2 x [256,1024] fp32)
  const size_t OFF_XB   = OFF_HF + 2097152;        // 67,108,864 B ([B,T,D] bf16)
  unsigned short* packed = (unsigned short*)(ws + OFF_PACK);
  unsigned short* hb     = (unsigned short*)(ws + OFF_HB);
  float*          hfm    = (float*)(ws + OFF_HF);
  unsigned short* xbm    = (unsigned short*)(ws + OFF_XB);
  const bool xbf = ws_size >= OFF_XB + (size_t)67108864;

  pack_weights<<<dim3(2304), dim3(256), 0, stream>>>(Wz, Wr, W, Uz, Ur, U, packed);
  if (xbf) cvt_x<<<dim3(2048), dim3(256), 0, stream>>>(x, xbm);

  const int HB = Bb * Hh;
  for (int t = 0; t < Tt; ++t) {
    const int rd = t & 1, wr = rd ^ 1;
    const unsigned short* hbs = hb  + (size_t)rd * HB;
    unsigned short*       hbd = hb  + (size_t)wr * HB;
    const float*          hfs = hfm + (size_t)rd * HB;
    float*                hfd = hfm + (size_t)wr * HB;
    if (t == 0) {
      if (xbf) gru_step<true,  true ><<<dim3(256), dim3(256), 0, stream>>>(x, xbm, packed, hbs, hbd, hfs, hfd, t);
      else     gru_step<true,  false><<<dim3(256), dim3(256), 0, stream>>>(x, xbm, packed, hbs, hbd, hfs, hfd, t);
    } else {
      if (xbf) gru_step<false, true ><<<dim3(256), dim3(256), 0, stream>>>(x, xbm, packed, hbs, hbd, hfs, hfd, t);
      else     gru_step<false, false><<<dim3(256), dim3(256), 0, stream>>>(x, xbm, packed, hbs, hbd, hfs, hfd, t);
    }
  }

  // after t=255, h_last (fp32) is in buffer (256 & 1) == 0
  classifier<<<dim3(4, 32), dim3(256), 0, stream>>>(hfm, Wph, bp, out);
  logsoftmax<<<dim3(256), dim3(256), 0, stream>>>(out);
}

// Round 13
// 3008.080 us; speedup vs baseline: 1.0674x; 1.0674x over previous
//
#include <hip/hip_runtime.h>
#include <hip/hip_bf16.h>

// Problem dims
#define Bb 256
#define Tt 256
#define Dd 512
#define Hh 1024
#define Cc 1000

typedef short  bf16x8 __attribute__((ext_vector_type(8)));
typedef float  f32x4  __attribute__((ext_vector_type(4)));
typedef unsigned short u16x8 __attribute__((ext_vector_type(8)));
typedef unsigned long long u64;

#define NCI 144
// packed: [cblk(64)][ci(144)][lane(64)][8 elems] bf16 = 9,437,184 B

// barrier region (dword indices, 32B-padded slots)
#define REG_OFF  0        // regcnt[8]
#define G0_OFF   64       // global start counter
#define LARR_OFF 128      // local arrivals [8][64]
#define AXC_OFF  4224     // per-XCD release counter [8]
#define RDY_OFF  4352     // per-XCD ready [8]
#define ARR_OFF  4480     // fallback per-WG arrivals [256]
#define BAR_BYTES 32768
#define POLL_CAP 20000000

__device__ __forceinline__ unsigned short f2bf(float f) {
  unsigned u = __float_as_uint(f);
  u += 0x7FFFu + ((u >> 16) & 1u);       // RNE
  return (unsigned short)(u >> 16);
}

__device__ __forceinline__ unsigned rmw_read(unsigned* p) {
  return __hip_atomic_fetch_add(p, 0u, __ATOMIC_RELAXED, __HIP_MEMORY_SCOPE_AGENT);
}
__device__ __forceinline__ void rmw_set(unsigned* p, unsigned v) {
  __hip_atomic_exchange(p, v, __ATOMIC_RELAXED, __HIP_MEMORY_SCOPE_AGENT);
}
__device__ __forceinline__ void rel_set(unsigned* p, unsigned v) {
  // atomic-exchange-RELEASE: emits buffer_wbl2 (cache-wide L2 writeback) before
  // the exchange — the ONLY store-side publish proven to work (R6 vs R11).
  __hip_atomic_exchange(p, v, __ATOMIC_RELEASE, __HIP_MEMORY_SCOPE_AGENT);
}

// ---------------- pack weights into MFMA-fragment order (bf16) ----------------
__global__ void pack_weights(const float* __restrict__ Wz, const float* __restrict__ Wr,
                             const float* __restrict__ W,  const float* __restrict__ Uz,
                             const float* __restrict__ Ur, const float* __restrict__ U,
                             unsigned short* __restrict__ packed) {
  int tid = blockIdx.x * 256 + threadIdx.x;
  if (tid >= 64 * NCI * 64) return;
  int lane = tid & 63;
  int rest = tid >> 6;
  int ci   = rest % NCI;
  int c    = rest / NCI;
  int j    = (c << 4) + (lane & 15);
  int kg   = lane >> 4;
  const float* src; int kb;
  if      (ci < 16)  { src = Wz; kb = ci*32; }
  else if (ci < 48)  { src = Uz; kb = (ci-16)*32; }
  else if (ci < 64)  { src = Wr; kb = (ci-48)*32; }
  else if (ci < 96)  { src = Ur; kb = (ci-64)*32; }
  else if (ci < 112) { src = W;  kb = (ci-96)*32; }
  else               { src = U;  kb = (ci-112)*32; }
  int k0 = kb + kg*8;
  u16x8 o;
  #pragma unroll
  for (int e = 0; e < 8; ++e) o[e] = f2bf(src[(size_t)(k0+e)*Hh + j]);
  *(u16x8*)(packed + (size_t)tid*8) = o;
}

// ---------------- x fp32 -> bf16 ----------------
__global__ void cvt_x(const float* __restrict__ x, unsigned short* __restrict__ xb) {
  const int n4 = (Bb*Tt*Dd)/4;
  for (int i = blockIdx.x*256 + threadIdx.x; i < n4; i += gridDim.x*256) {
    f32x4 v = *(const f32x4*)(x + (size_t)i*4);
    unsigned short o[4];
    #pragma unroll
    for (int e = 0; e < 4; ++e) o[e] = f2bf(v[e]);
    *(u64*)(xb + (size_t)i*4) = *(u64*)o;
  }
}

// ---------------- persistent GRU scan: 8 wbl2 + 8 inv per step ----------------
// Protocol (R13): producers cached-store h -> syncthreads (vmcnt drain: stores
// in own-XCD L2) -> relaxed RMW arrive LARR[xcd][idx]. Per-XCD leader: polls
// members' LARR -> ONE atomic-exchange-RELEASE on AXC[xcd] (buffer_wbl2 is
// cache-wide: publishes ALL members' dirty h-lines to MALL) -> polls 8 AXC ->
// ONE fence(ACQUIRE)=buffer_inv (own L2) -> RDY[xcd]. Members poll RDY, then
// plain cached h loads (L2 miss -> MALL, fresh). Fallback = exact R6.
template<bool XBF>
__global__ void __launch_bounds__(256, 1)
gru_scan(const float* __restrict__ x, const unsigned short* __restrict__ xb,
         const unsigned short* __restrict__ packed,
         float* __restrict__ hf, unsigned short* __restrict__ hb,
         unsigned* __restrict__ bar) {
  __shared__ short lds[NCI * 512];                     // 147,456 B weight slice
  __shared__ int sh_idx, sh_xcc, sh_members;

  const int wg   = blockIdx.x;
  const int cblk = wg & 63;
  const int rblk = wg >> 6;
  const int tid  = threadIdx.x;
  const int lane = tid & 63;
  const int wave = tid >> 6;

  { // stage weights into LDS once for all 256 steps
    const u16x8* s8 = (const u16x8*)(packed + (size_t)cblk * (NCI * 512));
    u16x8* d8 = (u16x8*)lds;
    #pragma unroll
    for (int i = 0; i < 36; ++i) d8[tid + i*256] = s8[tid + i*256];
  }

  // ---- registration: physical XCD id + member index ----
  unsigned xccr;
  asm("s_getreg_b32 %0, hwreg(20, 0, 4)" : "=s"(xccr));   // HW_REG_XCC_ID [m09]
  if (tid == 0) {
    int myx = (int)(xccr & 7u);
    unsigned idx = __hip_atomic_fetch_add(&bar[REG_OFF + myx*8], 1u,
                        __ATOMIC_RELAXED, __HIP_MEMORY_SCOPE_AGENT);
    sh_idx = (int)idx; sh_xcc = myx;
    __hip_atomic_fetch_add(&bar[G0_OFF], 1u, __ATOMIC_RELAXED, __HIP_MEMORY_SCOPE_AGENT);
  }
  __syncthreads();
  const int idx = sh_idx, myx = sh_xcc;
  if (tid == 0) {                      // start barrier, then final member count
    int cap = 0;
    while (rmw_read(&bar[G0_OFF]) < 256u && ++cap < POLL_CAP)
      __builtin_amdgcn_s_sleep(2);
    sh_members = (int)rmw_read(&bar[REG_OFF + myx*8]);
  }
  __syncthreads();
  const int  members  = sh_members;
  const bool fastmode = (members >= 1 && members <= 60);
  const bool leader   = (idx == 0);
  unsigned lanecnt = 0;                // wave0 lane<8: members per XCD
  if (wave == 0 && lane < 8) lanecnt = rmw_read(&bar[REG_OFF + lane*8]);

  const int arow = lane & 15;
  const int kg   = lane >> 4;
  const int b    = rblk*64 + wave*16 + arow;
  const int crow = rblk*64 + wave*16 + kg*4;
  const int j    = (cblk << 4) + arow;

  const float*          xrow  = x  + (size_t)b * Tt * Dd;
  const unsigned short* xbrow = xb + (size_t)b * Tt * Dd;

  f32x4 hold = {0.f,0.f,0.f,0.f};

  // prefetch x_0
  bf16x8 xa[16];
  if constexpr (XBF) {
    #pragma unroll
    for (int kk = 0; kk < 16; ++kk) xa[kk] = *(const bf16x8*)(xbrow + kk*32 + kg*8);
  } else {
    #pragma unroll
    for (int kk = 0; kk < 16; ++kk) {
      f32x4 v0 = *(const f32x4*)(xrow + kk*32 + kg*8);
      f32x4 v1 = *(const f32x4*)(xrow + kk*32 + kg*8 + 4);
      bf16x8 a;
      #pragma unroll
      for (int e = 0; e < 4; ++e) { ((unsigned short*)&a)[e] = f2bf(v0[e]); ((unsigned short*)&a)[e+4] = f2bf(v1[e]); }
      xa[kk] = a;
    }
  }

  for (int t = 0; t < Tt; ++t) {
    // ---- wave0: wait for h[t] ----
    if (t > 0 && wave == 0) {
      const unsigned tgt = (unsigned)t;
      if (fastmode) {
        if (leader) {
          int cap = 0;
          for (;;) {                   // own XCD members' arrivals
            unsigned v = (lane < members)
                ? rmw_read(&bar[LARR_OFF + (myx*64 + lane)*8]) : tgt;
            if (__all((int)(v >= tgt))) break;
            if (++cap > POLL_CAP) break;
            __builtin_amdgcn_s_sleep(1);
          }
          if (lane == 0) rel_set(&bar[AXC_OFF + myx*8], tgt);   // ONE wbl2/XCD/step
          cap = 0;
          for (;;) {                   // all 8 XCDs flushed?
            unsigned v = (lane < 8 && lanecnt > 0)
                ? rmw_read(&bar[AXC_OFF + lane*8]) : tgt;
            if (__all((int)(v >= tgt))) break;
            if (++cap > POLL_CAP) break;
            __builtin_amdgcn_s_sleep(1);
          }
          __builtin_amdgcn_fence(__ATOMIC_ACQUIRE, "agent");    // ONE inv/XCD/step
          if (lane == 0) rmw_set(&bar[RDY_OFF + myx*8], tgt);
        } else {
          int cap = 0;
          while (rmw_read(&bar[RDY_OFF + myx*8]) < tgt && ++cap < POLL_CAP)
            __builtin_amdgcn_s_sleep(1);
        }
      } else {
        // fallback: exact R6 (release'd per-WG arrivals + per-WG acquire)
        int cap = 0;
        for (;;) {
          unsigned v = rmw_read(&bar[ARR_OFF + (rblk*64 + lane)*8]);
          if (__all((int)(v >= tgt))) break;
          if (++cap > POLL_CAP) break;
          __builtin_amdgcn_s_sleep(1);
        }
        __builtin_amdgcn_fence(__ATOMIC_ACQUIRE, "agent");
      }
    }

    f32x4 az  = {0.f,0.f,0.f,0.f};
    f32x4 arr = {0.f,0.f,0.f,0.f};
    f32x4 axh = {0.f,0.f,0.f,0.f};
    f32x4 ahu = {0.f,0.f,0.f,0.f};

    // ---- x-part MFMAs (waves 1-3 run during wave0's wait) ----
    #pragma unroll
    for (int kk = 0; kk < 16; ++kk) {
      bf16x8 bz = *(const bf16x8*)&lds[(0  + kk)*512 + lane*8];
      bf16x8 br = *(const bf16x8*)&lds[(48 + kk)*512 + lane*8];
      bf16x8 bx = *(const bf16x8*)&lds[(96 + kk)*512 + lane*8];
      az  = __builtin_amdgcn_mfma_f32_16x16x32_bf16(xa[kk], bz, az , 0,0,0);
      arr = __builtin_amdgcn_mfma_f32_16x16x32_bf16(xa[kk], br, arr, 0,0,0);
      axh = __builtin_amdgcn_mfma_f32_16x16x32_bf16(xa[kk], bx, axh, 0,0,0);
    }

    // issue x_{t+1} prefetch (read-only data: in-flight loads are always safe)
    if (t + 1 < Tt) {
      if constexpr (XBF) {
        const unsigned short* xt = xbrow + (size_t)(t+1)*Dd;
        #pragma unroll
        for (int kk = 0; kk < 16; ++kk) xa[kk] = *(const bf16x8*)(xt + kk*32 + kg*8);
      } else {
        const float* xt = xrow + (size_t)(t+1)*Dd;
        #pragma unroll
        for (int kk = 0; kk < 16; ++kk) {
          f32x4 v0 = *(const f32x4*)(xt + kk*32 + kg*8);
          f32x4 v1 = *(const f32x4*)(xt + kk*32 + kg*8 + 4);
          bf16x8 a;
          #pragma unroll
          for (int e = 0; e < 4; ++e) { ((unsigned short*)&a)[e] = f2bf(v0[e]); ((unsigned short*)&a)[e+4] = f2bf(v1[e]); }
          xa[kk] = a;
        }
      }
    }

    if (t > 0) {
      __syncthreads();                 // all waves gated on wave0's wait

      // ---- h loads: plain cached (post-inv L2 miss -> MALL, fresh) ----
      const unsigned short* hrow = hb + (size_t)(t & 1)*(Bb*Hh) + (size_t)b*Hh;
      bf16x8 ha[32];
      #pragma unroll
      for (int kk = 0; kk < 32; ++kk)
        ha[kk] = *(const bf16x8*)(hrow + kk*32 + kg*8);

      // ---- h-part MFMAs ----
      #pragma unroll
      for (int kk = 0; kk < 32; ++kk) {
        bf16x8 bz = *(const bf16x8*)&lds[(16  + kk)*512 + lane*8];
        bf16x8 br = *(const bf16x8*)&lds[(64  + kk)*512 + lane*8];
        bf16x8 bu = *(const bf16x8*)&lds[(112 + kk)*512 + lane*8];
        az  = __builtin_amdgcn_mfma_f32_16x16x32_bf16(ha[kk], bz, az , 0,0,0);
        arr = __builtin_amdgcn_mfma_f32_16x16x32_bf16(ha[kk], br, arr, 0,0,0);
        ahu = __builtin_amdgcn_mfma_f32_16x16x32_bf16(ha[kk], bu, ahu, 0,0,0);
      }
    }

    // ---- gate epilogue ----
    unsigned short hv[4];
    #pragma unroll
    for (int e = 0; e < 4; ++e) {
      float z  = 1.f / (1.f + __expf(-az[e]));
      float r  = 1.f / (1.f + __expf(-arr[e]));
      float u  = axh[e] + ahu[e] * r;
      float hh = 2.f / (1.f + __expf(-2.f * u)) - 1.f;
      float hn = z*hold[e] + (1.f - z)*hh;
      hold[e]  = hn;
      hv[e]    = f2bf(hn);
    }

    if (t < Tt - 1) {
      unsigned short* hbw = hb + (size_t)((t+1) & 1)*(Bb*Hh);
      #pragma unroll
      for (int e = 0; e < 4; ++e) hbw[(size_t)(crow+e)*Hh + j] = hv[e];   // cached
      __syncthreads();               // vmcnt drained: stores are in own-XCD L2
      if (tid == 0) {
        unsigned tv = (unsigned)(t + 1);
        rmw_set(&bar[LARR_OFF + (myx*64 + idx)*8], tv);      // local arrive
        if (!fastmode) rel_set(&bar[ARR_OFF + wg*8], tv);    // R6 release arrive
      }
    } else {
      #pragma unroll
      for (int e = 0; e < 4; ++e) hf[(size_t)(crow+e)*Hh + j] = hold[e];
    }
  }
}

// ---------------- classifier: p = h_last @ W_ph + b_p ----------------
__global__ void classifier(const float* __restrict__ h, const float* __restrict__ Wph,
                           const float* __restrict__ bp, float* __restrict__ out) {
  __shared__ float hsm[8 * Hh];
  const int cb = blockIdx.x, bbk = blockIdx.y;
  const int tid = threadIdx.x;
  const float* h0 = h + (size_t)bbk * 8 * Hh;
  for (int i = tid; i < 8 * Hh; i += 256) {
    int r = i >> 10, k = i & (Hh - 1);
    hsm[k*8 + r] = h0[i];
  }
  __syncthreads();
  int c = cb*256 + tid;
  bool act = c < Cc;
  float acc[8] = {0,0,0,0,0,0,0,0};
  for (int k = 0; k < Hh; ++k) {
    float w = act ? Wph[(size_t)k*Cc + c] : 0.f;
    f32x4 h0v = *(const f32x4*)&hsm[k*8];
    f32x4 h1v = *(const f32x4*)&hsm[k*8 + 4];
    acc[0] += h0v[0]*w; acc[1] += h0v[1]*w; acc[2] += h0v[2]*w; acc[3] += h0v[3]*w;
    acc[4] += h1v[0]*w; acc[5] += h1v[1]*w; acc[6] += h1v[2]*w; acc[7] += h1v[3]*w;
  }
  if (act) {
    float bias = bp[c];
    #pragma unroll
    for (int r = 0; r < 8; ++r) out[(size_t)(bbk*8 + r)*Cc + c] = acc[r] + bias;
  }
}

// ---------------- in-place log_softmax over rows of [256,1000] ----------------
__global__ void logsoftmax(float* __restrict__ out) {
  __shared__ float sm[4];
  float* row = out + (size_t)blockIdx.x * Cc;
  const int tid = threadIdx.x;
  float m = -3.4e38f;
  for (int i = tid; i < Cc; i += 256) m = fmaxf(m, row[i]);
  #pragma unroll
  for (int o = 32; o; o >>= 1) m = fmaxf(m, __shfl_down(m, o, 64));
  if ((tid & 63) == 0) sm[tid >> 6] = m;
  __syncthreads();
  m = fmaxf(fmaxf(sm[0], sm[1]), fmaxf(sm[2], sm[3]));
  __syncthreads();
  float s = 0.f;
  for (int i = tid; i < Cc; i += 256) s += __expf(row[i] - m);
  #pragma unroll
  for (int o = 32; o; o >>= 1) s += __shfl_down(s, o, 64);
  if ((tid & 63) == 0) sm[tid >> 6] = s;
  __syncthreads();
  s = sm[0] + sm[1] + sm[2] + sm[3];
  float lse = m + __logf(s);
  for (int i = tid; i < Cc; i += 256) row[i] -= lse;
}

extern "C" void kernel_launch(void* const* d_in, const int* in_sizes, int n_in,
                              void* d_out, int out_size, void* d_ws, size_t ws_size,
                              hipStream_t stream) {
  (void)in_sizes; (void)n_in; (void)out_size;
  const float* x   = (const float*)d_in[0];
  const float* Wz  = (const float*)d_in[1];
  const float* Wr  = (const float*)d_in[2];
  const float* W   = (const float*)d_in[3];
  const float* Uz  = (const float*)d_in[4];
  const float* Ur  = (const float*)d_in[5];
  const float* U   = (const float*)d_in[6];
  const float* Wph = (const float*)d_in[7];
  const float* bp  = (const float*)d_in[8];
  float* out = (float*)d_out;

  char* ws = (char*)d_ws;
  const size_t OFF_PACK = 0;                       // 9,437,184 B
  const size_t OFF_HF   = 9437184;                 // 1,048,576 B (final h fp32)
  const size_t OFF_HB   = OFF_HF + 1048576;        // 1,048,576 B (2 x bf16 h)
  const size_t OFF_BAR  = OFF_HB + 1048576;        // 32,768 B barrier region
  const size_t OFF_XB   = OFF_BAR + 32768;         // 67,108,864 B (x bf16)
  unsigned short* packed = (unsigned short*)(ws + OFF_PACK);
  float*          hf     = (float*)(ws + OFF_HF);
  unsigned short* hb     = (unsigned short*)(ws + OFF_HB);
  unsigned*       bar    = (unsigned*)(ws + OFF_BAR);
  unsigned short* xbm    = (unsigned short*)(ws + OFF_XB);
  const bool xbf = ws_size >= OFF_XB + (size_t)67108864;

  hipMemsetAsync(bar, 0, BAR_BYTES, stream);       // fresh flags each replay
  pack_weights<<<dim3(2304), dim3(256), 0, stream>>>(Wz, Wr, W, Uz, Ur, U, packed);
  if (xbf) cvt_x<<<dim3(2048), dim3(256), 0, stream>>>(x, xbm);

  void* args[] = { (void*)&x, (void*)&xbm, (void*)&packed, (void*)&hf, (void*)&hb, (void*)&bar };
  if (xbf) {
    hipLaunchCooperativeKernel(reinterpret_cast<void*>(&gru_scan<true>),
                               dim3(256), dim3(256), args, 0, stream);
  } else {
    hipLaunchCooperativeKernel(reinterpret_cast<void*>(&gru_scan<false>),
                               dim3(256), dim3(256), args, 0, stream);
  }

  classifier<<<dim3(4, 32), dim3(256), 0, stream>>>(hf, Wph, bp, out);
  logsoftmax<<<dim3(256), dim3(256), 0, stream>>>(out);
}

// Round 15
// 2517.891 us; speedup vs baseline: 1.2752x; 1.1947x over previous
//
#include <hip/hip_runtime.h>
#include <hip/hip_bf16.h>

// Problem dims
#define Bb 256
#define Tt 256
#define Dd 512
#define Hh 1024
#define Cc 1000

typedef short  bf16x8 __attribute__((ext_vector_type(8)));
typedef float  f32x4  __attribute__((ext_vector_type(4)));
typedef unsigned short u16x8 __attribute__((ext_vector_type(8)));
typedef unsigned long long u64;

#define NCI 144
// packed: [cblk(64)][ci(144)][lane(64)][8 elems] bf16 = 9,437,184 B

// barrier region (dword indices, 32B-padded slots)
#define REG_OFF  0        // regcnt[8]
#define G0_OFF   64       // global start counter
#define LARR_OFF 128      // local arrivals [8][64]
#define AXC_OFF  4224     // per-XCD release counter [8]
#define RDY_OFF  4352     // per-XCD ready [8]
#define BAR_BYTES 32768
#define POLL_CAP 20000000

__device__ __forceinline__ unsigned short f2bf(float f) {
  unsigned u = __float_as_uint(f);
  u += 0x7FFFu + ((u >> 16) & 1u);       // RNE
  return (unsigned short)(u >> 16);
}

__device__ __forceinline__ unsigned rmw_read(unsigned* p) {
  return __hip_atomic_fetch_add(p, 0u, __ATOMIC_RELAXED, __HIP_MEMORY_SCOPE_AGENT);
}
__device__ __forceinline__ void rmw_set(unsigned* p, unsigned v) {
  __hip_atomic_exchange(p, v, __ATOMIC_RELAXED, __HIP_MEMORY_SCOPE_AGENT);
}
__device__ __forceinline__ void rel_set(unsigned* p, unsigned v) {
  // atomic-exchange-RELEASE: buffer_wbl2 (cache-wide own-L2 writeback) before the
  // swap — publishes ALL co-XCD WGs' cached stores to the MALL (R13-proven).
  __hip_atomic_exchange(p, v, __ATOMIC_RELEASE, __HIP_MEMORY_SCOPE_AGENT);
}

// ---------------- pack weights into MFMA-fragment order (bf16) ----------------
__global__ void pack_weights(const float* __restrict__ Wz, const float* __restrict__ Wr,
                             const float* __restrict__ W,  const float* __restrict__ Uz,
                             const float* __restrict__ Ur, const float* __restrict__ U,
                             unsigned short* __restrict__ packed) {
  int tid = blockIdx.x * 256 + threadIdx.x;
  if (tid >= 64 * NCI * 64) return;
  int lane = tid & 63;
  int rest = tid >> 6;
  int ci   = rest % NCI;
  int c    = rest / NCI;
  int j    = (c << 4) + (lane & 15);
  int kg   = lane >> 4;
  const float* src; int kb;
  if      (ci < 16)  { src = Wz; kb = ci*32; }
  else if (ci < 48)  { src = Uz; kb = (ci-16)*32; }
  else if (ci < 64)  { src = Wr; kb = (ci-48)*32; }
  else if (ci < 96)  { src = Ur; kb = (ci-64)*32; }
  else if (ci < 112) { src = W;  kb = (ci-96)*32; }
  else               { src = U;  kb = (ci-112)*32; }
  int k0 = kb + kg*8;
  u16x8 o;
  #pragma unroll
  for (int e = 0; e < 8; ++e) o[e] = f2bf(src[(size_t)(k0+e)*Hh + j]);
  *(u16x8*)(packed + (size_t)tid*8) = o;
}

// ---------------- x fp32 -> bf16 ----------------
__global__ void cvt_x(const float* __restrict__ x, unsigned short* __restrict__ xb) {
  const int n4 = (Bb*Tt*Dd)/4;
  for (int i = blockIdx.x*256 + threadIdx.x; i < n4; i += gridDim.x*256) {
    f32x4 v = *(const f32x4*)(x + (size_t)i*4);
    unsigned short o[4];
    #pragma unroll
    for (int e = 0; e < 4; ++e) o[e] = f2bf(v[e]);
    *(u64*)(xb + (size_t)i*4) = *(u64*)o;
  }
}

// ---------------- persistent GRU scan: pair-scoped R13 protocol ----------------
// Protocol = EXACTLY R13 (the only proven-safe order): cached stores ->
// syncthreads (vmcnt drain) -> relaxed arrive -> leader polls own-XCD members
// -> rel_set AXC (buffer_wbl2, publishes all members' dirty h-lines) ->
// cross-poll AXC -> fence(ACQUIRE)=buffer_inv -> RDY -> members poll RDY ->
// plain cached loads. R15 change: row-groups are mapped to XCD PAIRS via
// XCC_ID registration, so the cross-poll is over the pair partner only and
// the 4 pairs pace independently (no global slowest-WG coupling per step).
// Fallback (counts != 32/XCD): identical code with cross-poll over all 8.
template<bool XBF>
__global__ void __launch_bounds__(256, 1)
gru_scan(const float* __restrict__ x, const unsigned short* __restrict__ xb,
         const unsigned short* __restrict__ packed,
         float* __restrict__ hf, unsigned short* __restrict__ hb,
         unsigned* __restrict__ bar) {
  __shared__ short lds[NCI * 512];                     // 147,456 B weight slice
  __shared__ int sh_idx, sh_xcc, sh_members, sh_ok;

  const int wg   = blockIdx.x;
  const int tid  = threadIdx.x;
  const int lane = tid & 63;
  const int wave = tid >> 6;

  // ---- registration: physical XCD id + member index ----
  unsigned xccr;
  asm("s_getreg_b32 %0, hwreg(20, 0, 4)" : "=s"(xccr));   // HW_REG_XCC_ID [m09]
  if (tid == 0) {
    int myx = (int)(xccr & 7u);
    unsigned idx = __hip_atomic_fetch_add(&bar[REG_OFF + myx*8], 1u,
                        __ATOMIC_RELAXED, __HIP_MEMORY_SCOPE_AGENT);
    sh_idx = (int)idx; sh_xcc = myx;
    __hip_atomic_fetch_add(&bar[G0_OFF], 1u, __ATOMIC_RELAXED, __HIP_MEMORY_SCOPE_AGENT);
  }
  __syncthreads();
  const int idx = sh_idx, myx = sh_xcc;
  if (tid == 0) {                      // start barrier: counts final afterwards
    int cap = 0;
    while (rmw_read(&bar[G0_OFF]) < 256u && ++cap < POLL_CAP)
      __builtin_amdgcn_s_sleep(2);
    int pairok = 1;
    unsigned cm = 0;
    for (int i = 0; i < 8; ++i) {
      unsigned c = rmw_read(&bar[REG_OFF + i*8]);
      if (c != 32u) pairok = 0;
      if (i == myx) cm = c;
    }
    sh_ok = pairok;
    sh_members = (int)cm;
  }
  __syncthreads();
  const bool pairmode = (sh_ok != 0);
  const int  members  = sh_members;
  const bool leader   = (idx == 0);
  unsigned lanecnt = 0;                // wave0 lane<8: members per XCD (final)
  if (wave == 0 && lane < 8) lanecnt = rmw_read(&bar[REG_OFF + lane*8]);

  // ---- work assignment (pair-local in fastmode, wg-based in fallback) ----
  const int rgroup = pairmode ? (myx >> 1) : (wg >> 6);
  const int cblk   = pairmode ? ((myx & 1) * 32 + idx) : (wg & 63);

  { // stage weights into LDS once for all 256 steps (needs cblk)
    const u16x8* s8 = (const u16x8*)(packed + (size_t)cblk * (NCI * 512));
    u16x8* d8 = (u16x8*)lds;
    #pragma unroll
    for (int i = 0; i < 36; ++i) d8[tid + i*256] = s8[tid + i*256];
  }
  __syncthreads();

  const int arow = lane & 15;
  const int kg   = lane >> 4;
  const int b    = rgroup*64 + wave*16 + arow;
  const int crow = rgroup*64 + wave*16 + kg*4;
  const int j    = (cblk << 4) + arow;

  const float*          xrow  = x  + (size_t)b * Tt * Dd;
  const unsigned short* xbrow = xb + (size_t)b * Tt * Dd;

  f32x4 hold = {0.f,0.f,0.f,0.f};

  // prefetch x_0
  bf16x8 xa[16];
  if constexpr (XBF) {
    #pragma unroll
    for (int kk = 0; kk < 16; ++kk) xa[kk] = *(const bf16x8*)(xbrow + kk*32 + kg*8);
  } else {
    #pragma unroll
    for (int kk = 0; kk < 16; ++kk) {
      f32x4 v0 = *(const f32x4*)(xrow + kk*32 + kg*8);
      f32x4 v1 = *(const f32x4*)(xrow + kk*32 + kg*8 + 4);
      bf16x8 a;
      #pragma unroll
      for (int e = 0; e < 4; ++e) { ((unsigned short*)&a)[e] = f2bf(v0[e]); ((unsigned short*)&a)[e+4] = f2bf(v1[e]); }
      xa[kk] = a;
    }
  }

  for (int t = 0; t < Tt; ++t) {
    // ---- wave0: wait for h[t] (R13 hop order; pair-narrowed cross-poll) ----
    if (t > 0 && wave == 0) {
      const unsigned tgt = (unsigned)t;
      if (leader) {
        int cap = 0;
        for (;;) {                     // own XCD members' arrivals
          unsigned v = (lane < members)
              ? rmw_read(&bar[LARR_OFF + (myx*64 + lane)*8]) : tgt;
          if (__all((int)(v >= tgt))) break;
          if (++cap > POLL_CAP) break;
          __builtin_amdgcn_s_sleep(1);
        }
        if (lane == 0) rel_set(&bar[AXC_OFF + myx*8], tgt);   // wbl2 + publish
        cap = 0;
        if (pairmode) {
          for (;;) {                   // partner XCD only
            unsigned v = (lane == 0)
                ? rmw_read(&bar[AXC_OFF + (myx^1)*8]) : tgt;
            if (__all((int)(v >= tgt))) break;
            if (++cap > POLL_CAP) break;
            __builtin_amdgcn_s_sleep(1);
          }
        } else {
          for (;;) {                   // all 8 XCDs (R13 global)
            unsigned v = (lane < 8 && lanecnt > 0)
                ? rmw_read(&bar[AXC_OFF + lane*8]) : tgt;
            if (__all((int)(v >= tgt))) break;
            if (++cap > POLL_CAP) break;
            __builtin_amdgcn_s_sleep(1);
          }
        }
        __builtin_amdgcn_fence(__ATOMIC_ACQUIRE, "agent");    // inv AFTER all wbl2
        if (lane == 0) rmw_set(&bar[RDY_OFF + myx*8], tgt);
      } else {
        int cap = 0;
        while (rmw_read(&bar[RDY_OFF + myx*8]) < tgt && ++cap < POLL_CAP)
          __builtin_amdgcn_s_sleep(1);
      }
    }

    f32x4 az  = {0.f,0.f,0.f,0.f};
    f32x4 arr = {0.f,0.f,0.f,0.f};
    f32x4 axh = {0.f,0.f,0.f,0.f};
    f32x4 ahu = {0.f,0.f,0.f,0.f};

    // ---- x-part MFMAs (waves 1-3 run during wave0's wait) ----
    #pragma unroll
    for (int kk = 0; kk < 16; ++kk) {
      bf16x8 bz = *(const bf16x8*)&lds[(0  + kk)*512 + lane*8];
      bf16x8 br = *(const bf16x8*)&lds[(48 + kk)*512 + lane*8];
      bf16x8 bx = *(const bf16x8*)&lds[(96 + kk)*512 + lane*8];
      az  = __builtin_amdgcn_mfma_f32_16x16x32_bf16(xa[kk], bz, az , 0,0,0);
      arr = __builtin_amdgcn_mfma_f32_16x16x32_bf16(xa[kk], br, arr, 0,0,0);
      axh = __builtin_amdgcn_mfma_f32_16x16x32_bf16(xa[kk], bx, axh, 0,0,0);
    }

    // issue x_{t+1} prefetch (lands in registers; immune to later inv)
    if (t + 1 < Tt) {
      if constexpr (XBF) {
        const unsigned short* xt = xbrow + (size_t)(t+1)*Dd;
        #pragma unroll
        for (int kk = 0; kk < 16; ++kk) xa[kk] = *(const bf16x8*)(xt + kk*32 + kg*8);
      } else {
        const float* xt = xrow + (size_t)(t+1)*Dd;
        #pragma unroll
        for (int kk = 0; kk < 16; ++kk) {
          f32x4 v0 = *(const f32x4*)(xt + kk*32 + kg*8);
          f32x4 v1 = *(const f32x4*)(xt + kk*32 + kg*8 + 4);
          bf16x8 a;
          #pragma unroll
          for (int e = 0; e < 4; ++e) { ((unsigned short*)&a)[e] = f2bf(v0[e]); ((unsigned short*)&a)[e+4] = f2bf(v1[e]); }
          xa[kk] = a;
        }
      }
    }

    if (t > 0) {
      __syncthreads();                 // all waves gated on wave0's wait

      // ---- h loads: plain cached (post-inv L2 miss -> MALL, fresh) ----
      const unsigned short* hrow = hb + (size_t)(t & 1)*(Bb*Hh) + (size_t)b*Hh;
      bf16x8 ha[32];
      #pragma unroll
      for (int kk = 0; kk < 32; ++kk)
        ha[kk] = *(const bf16x8*)(hrow + kk*32 + kg*8);

      // ---- h-part MFMAs ----
      #pragma unroll
      for (int kk = 0; kk < 32; ++kk) {
        bf16x8 bz = *(const bf16x8*)&lds[(16  + kk)*512 + lane*8];
        bf16x8 br = *(const bf16x8*)&lds[(64  + kk)*512 + lane*8];
        bf16x8 bu = *(const bf16x8*)&lds[(112 + kk)*512 + lane*8];
        az  = __builtin_amdgcn_mfma_f32_16x16x32_bf16(ha[kk], bz, az , 0,0,0);
        arr = __builtin_amdgcn_mfma_f32_16x16x32_bf16(ha[kk], br, arr, 0,0,0);
        ahu = __builtin_amdgcn_mfma_f32_16x16x32_bf16(ha[kk], bu, ahu, 0,0,0);
      }
    }

    // ---- gate epilogue ----
    unsigned short hv[4];
    #pragma unroll
    for (int e = 0; e < 4; ++e) {
      float z  = 1.f / (1.f + __expf(-az[e]));
      float r  = 1.f / (1.f + __expf(-arr[e]));
      float u  = axh[e] + ahu[e] * r;
      float hh = 2.f / (1.f + __expf(-2.f * u)) - 1.f;
      float hn = z*hold[e] + (1.f - z)*hh;
      hold[e]  = hn;
      hv[e]    = f2bf(hn);
    }

    if (t < Tt - 1) {
      unsigned short* hbw = hb + (size_t)((t+1) & 1)*(Bb*Hh);
      #pragma unroll
      for (int e = 0; e < 4; ++e) hbw[(size_t)(crow+e)*Hh + j] = hv[e];   // cached
      __syncthreads();               // vmcnt drained: stores are in own-XCD L2
      if (tid == 0)
        rmw_set(&bar[LARR_OFF + (myx*64 + idx)*8], (unsigned)(t + 1));
    } else {
      #pragma unroll
      for (int e = 0; e < 4; ++e) hf[(size_t)(crow+e)*Hh + j] = hold[e];
    }
  }
}

// ---------------- classifier: p = h_last @ W_ph + b_p ----------------
__global__ void classifier(const float* __restrict__ h, const float* __restrict__ Wph,
                           const float* __restrict__ bp, float* __restrict__ out) {
  __shared__ float hsm[8 * Hh];
  const int cb = blockIdx.x, bbk = blockIdx.y;
  const int tid = threadIdx.x;
  const float* h0 = h + (size_t)bbk * 8 * Hh;
  for (int i = tid; i < 8 * Hh; i += 256) {
    int r = i >> 10, k = i & (Hh - 1);
    hsm[k*8 + r] = h0[i];
  }
  __syncthreads();
  int c = cb*256 + tid;
  bool act = c < Cc;
  float acc[8] = {0,0,0,0,0,0,0,0};
  for (int k = 0; k < Hh; ++k) {
    float w = act ? Wph[(size_t)k*Cc + c] : 0.f;
    f32x4 h0v = *(const f32x4*)&hsm[k*8];
    f32x4 h1v = *(const f32x4*)&hsm[k*8 + 4];
    acc[0] += h0v[0]*w; acc[1] += h0v[1]*w; acc[2] += h0v[2]*w; acc[3] += h0v[3]*w;
    acc[4] += h1v[0]*w; acc[5] += h1v[1]*w; acc[6] += h1v[2]*w; acc[7] += h1v[3]*w;
  }
  if (act) {
    float bias = bp[c];
    #pragma unroll
    for (int r = 0; r < 8; ++r) out[(size_t)(bbk*8 + r)*Cc + c] = acc[r] + bias;
  }
}

// ---------------- in-place log_softmax over rows of [256,1000] ----------------
__global__ void logsoftmax(float* __restrict__ out) {
  __shared__ float sm[4];
  float* row = out + (size_t)blockIdx.x * Cc;
  const int tid = threadIdx.x;
  float m = -3.4e38f;
  for (int i = tid; i < Cc; i += 256) m = fmaxf(m, row[i]);
  #pragma unroll
  for (int o = 32; o; o >>= 1) m = fmaxf(m, __shfl_down(m, o, 64));
  if ((tid & 63) == 0) sm[tid >> 6] = m;
  __syncthreads();
  m = fmaxf(fmaxf(sm[0], sm[1]), fmaxf(sm[2], sm[3]));
  __syncthreads();
  float s = 0.f;
  for (int i = tid; i < Cc; i += 256) s += __expf(row[i] - m);
  #pragma unroll
  for (int o = 32; o; o >>= 1) s += __shfl_down(s, o, 64);
  if ((tid & 63) == 0) sm[tid >> 6] = s;
  __syncthreads();
  s = sm[0] + sm[1] + sm[2] + sm[3];
  float lse = m + __logf(s);
  for (int i = tid; i < Cc; i += 256) row[i] -= lse;
}

extern "C" void kernel_launch(void* const* d_in, const int* in_sizes, int n_in,
                              void* d_out, int out_size, void* d_ws, size_t ws_size,
                              hipStream_t stream) {
  (void)in_sizes; (void)n_in; (void)out_size;
  const float* x   = (const float*)d_in[0];
  const float* Wz  = (const float*)d_in[1];
  const float* Wr  = (const float*)d_in[2];
  const float* W   = (const float*)d_in[3];
  const float* Uz  = (const float*)d_in[4];
  const float* Ur  = (const float*)d_in[5];
  const float* U   = (const float*)d_in[6];
  const float* Wph = (const float*)d_in[7];
  const float* bp  = (const float*)d_in[8];
  float* out = (float*)d_out;

  char* ws = (char*)d_ws;
  const size_t OFF_PACK = 0;                       // 9,437,184 B
  const size_t OFF_HF   = 9437184;                 // 1,048,576 B (final h fp32)
  const size_t OFF_HB   = OFF_HF + 1048576;        // 1,048,576 B (2 x bf16 h)
  const size_t OFF_BAR  = OFF_HB + 1048576;        // 32,768 B barrier region
  const size_t OFF_XB   = OFF_BAR + 32768;         // 67,108,864 B (x bf16)
  unsigned short* packed = (unsigned short*)(ws + OFF_PACK);
  float*          hf     = (float*)(ws + OFF_HF);
  unsigned short* hb     = (unsigned short*)(ws + OFF_HB);
  unsigned*       bar    = (unsigned*)(ws + OFF_BAR);
  unsigned short* xbm    = (unsigned short*)(ws + OFF_XB);
  const bool xbf = ws_size >= OFF_XB + (size_t)67108864;

  hipMemsetAsync(bar, 0, BAR_BYTES, stream);       // fresh flags each replay
  pack_weights<<<dim3(2304), dim3(256), 0, stream>>>(Wz, Wr, W, Uz, Ur, U, packed);
  if (xbf) cvt_x<<<dim3(2048), dim3(256), 0, stream>>>(x, xbm);

  void* args[] = { (void*)&x, (void*)&xbm, (void*)&packed, (void*)&hf, (void*)&hb, (void*)&bar };
  if (xbf) {
    hipLaunchCooperativeKernel(reinterpret_cast<void*>(&gru_scan<true>),
                               dim3(256), dim3(256), args, 0, stream);
  } else {
    hipLaunchCooperativeKernel(reinterpret_cast<void*>(&gru_scan<false>),
                               dim3(256), dim3(256), args, 0, stream);
  }

  classifier<<<dim3(4, 32), dim3(256), 0, stream>>>(hf, Wph, bp, out);
  logsoftmax<<<dim3(256), dim3(256), 0, stream>>>(out);
}

// Round 17
// 2503.293 us; speedup vs baseline: 1.2826x; 1.0058x over previous
//
#include <hip/hip_runtime.h>
#include <hip/hip_bf16.h>

// Problem dims
#define Bb 256
#define Tt 256
#define Dd 512
#define Hh 1024
#define Cc 1000

typedef short  bf16x8 __attribute__((ext_vector_type(8)));
typedef float  f32x4  __attribute__((ext_vector_type(4)));
typedef unsigned short u16x8 __attribute__((ext_vector_type(8)));
typedef unsigned long long u64;

#define NCI 144
// packed: [cblk(64)][ci(144)][lane(64)][8 elems] bf16 = 9,437,184 B

// barrier region (dword indices, 32B-padded slots)
#define REG_OFF  0        // regcnt[8]
#define G0_OFF   64       // global start counter
#define LARR_OFF 128      // local arrivals [8][64]
#define AXC_OFF  4224     // per-XCD release counter [8]
#define RDY_OFF  4352     // per-XCD ready [8]
#define BAR_BYTES 32768
#define POLL_CAP 20000000

__device__ __forceinline__ unsigned short f2bf(float f) {
  unsigned u = __float_as_uint(f);
  u += 0x7FFFu + ((u >> 16) & 1u);       // RNE
  return (unsigned short)(u >> 16);
}

__device__ __forceinline__ unsigned rmw_read(unsigned* p) {
  return __hip_atomic_fetch_add(p, 0u, __ATOMIC_RELAXED, __HIP_MEMORY_SCOPE_AGENT);
}
__device__ __forceinline__ void rmw_set(unsigned* p, unsigned v) {
  __hip_atomic_exchange(p, v, __ATOMIC_RELAXED, __HIP_MEMORY_SCOPE_AGENT);
}
__device__ __forceinline__ void rel_set(unsigned* p, unsigned v) {
  // atomic-exchange-RELEASE: buffer_wbl2 (cache-wide own-L2 writeback) before the
  // swap — publishes ALL co-XCD WGs' cached stores to the MALL (R13-proven).
  __hip_atomic_exchange(p, v, __ATOMIC_RELEASE, __HIP_MEMORY_SCOPE_AGENT);
}

// ---------------- pack weights into MFMA-fragment order (bf16) ----------------
__global__ void pack_weights(const float* __restrict__ Wz, const float* __restrict__ Wr,
                             const float* __restrict__ W,  const float* __restrict__ Uz,
                             const float* __restrict__ Ur, const float* __restrict__ U,
                             unsigned short* __restrict__ packed) {
  int tid = blockIdx.x * 256 + threadIdx.x;
  if (tid >= 64 * NCI * 64) return;
  int lane = tid & 63;
  int rest = tid >> 6;
  int ci   = rest % NCI;
  int c    = rest / NCI;
  int j    = (c << 4) + (lane & 15);
  int kg   = lane >> 4;
  const float* src; int kb;
  if      (ci < 16)  { src = Wz; kb = ci*32; }
  else if (ci < 48)  { src = Uz; kb = (ci-16)*32; }
  else if (ci < 64)  { src = Wr; kb = (ci-48)*32; }
  else if (ci < 96)  { src = Ur; kb = (ci-64)*32; }
  else if (ci < 112) { src = W;  kb = (ci-96)*32; }
  else               { src = U;  kb = (ci-112)*32; }
  int k0 = kb + kg*8;
  u16x8 o;
  #pragma unroll
  for (int e = 0; e < 8; ++e) o[e] = f2bf(src[(size_t)(k0+e)*Hh + j]);
  *(u16x8*)(packed + (size_t)tid*8) = o;
}

// ---------------- x fp32 -> bf16 ----------------
__global__ void cvt_x(const float* __restrict__ x, unsigned short* __restrict__ xb) {
  const int n4 = (Bb*Tt*Dd)/4;
  for (int i = blockIdx.x*256 + threadIdx.x; i < n4; i += gridDim.x*256) {
    f32x4 v = *(const f32x4*)(x + (size_t)i*4);
    unsigned short o[4];
    #pragma unroll
    for (int e = 0; e < 4; ++e) o[e] = f2bf(v[e]);
    *(u64*)(xb + (size_t)i*4) = *(u64*)o;
  }
}

// ---------------- persistent GRU scan: pair-scoped R13 protocol ----------------
// Protocol = EXACTLY R13 (the only proven-safe order): cached stores ->
// syncthreads (vmcnt drain) -> relaxed arrive -> leader polls own-XCD members
// -> rel_set AXC (buffer_wbl2, publishes all members' dirty h-lines) ->
// cross-poll AXC -> fence(ACQUIRE)=buffer_inv -> RDY -> members poll RDY ->
// plain cached loads. Row-groups are mapped to XCD PAIRS via XCC_ID
// registration, so the cross-poll is over the pair partner only and the 4
// pairs pace independently. Fallback (counts != 32/XCD): cross-poll all 8.
template<bool XBF>
__global__ void __launch_bounds__(256, 1)
gru_scan(const float* __restrict__ x, const unsigned short* __restrict__ xb,
         const unsigned short* __restrict__ packed,
         float* __restrict__ hf, unsigned short* __restrict__ hb,
         unsigned* __restrict__ bar) {
  __shared__ short lds[NCI * 512];                     // 147,456 B weight slice
  __shared__ int sh_idx, sh_xcc, sh_members, sh_ok;

  const int wg   = blockIdx.x;
  const int tid  = threadIdx.x;
  const int lane = tid & 63;
  const int wave = tid >> 6;

  // ---- registration: physical XCD id + member index ----
  unsigned xccr;
  asm("s_getreg_b32 %0, hwreg(20, 0, 4)" : "=s"(xccr));   // HW_REG_XCC_ID [m09]
  if (tid == 0) {
    int myx = (int)(xccr & 7u);
    unsigned idx = __hip_atomic_fetch_add(&bar[REG_OFF + myx*8], 1u,
                        __ATOMIC_RELAXED, __HIP_MEMORY_SCOPE_AGENT);
    sh_idx = (int)idx; sh_xcc = myx;
    __hip_atomic_fetch_add(&bar[G0_OFF], 1u, __ATOMIC_RELAXED, __HIP_MEMORY_SCOPE_AGENT);
  }
  __syncthreads();
  const int idx = sh_idx, myx = sh_xcc;
  if (tid == 0) {                      // start barrier: counts final afterwards
    int cap = 0;
    while (rmw_read(&bar[G0_OFF]) < 256u && ++cap < POLL_CAP)
      __builtin_amdgcn_s_sleep(2);
    int pairok = 1;
    unsigned cm = 0;
    for (int i = 0; i < 8; ++i) {
      unsigned c = rmw_read(&bar[REG_OFF + i*8]);
      if (c != 32u) pairok = 0;
      if (i == myx) cm = c;
    }
    sh_ok = pairok;
    sh_members = (int)cm;
  }
  __syncthreads();
  const bool pairmode = (sh_ok != 0);
  const int  members  = sh_members;
  const bool leader   = (idx == 0);
  unsigned lanecnt = 0;                // wave0 lane<8: members per XCD (final)
  if (wave == 0 && lane < 8) lanecnt = rmw_read(&bar[REG_OFF + lane*8]);

  // ---- work assignment (pair-local in fastmode, wg-based in fallback) ----
  const int rgroup = pairmode ? (myx >> 1) : (wg >> 6);
  const int cblk   = pairmode ? ((myx & 1) * 32 + idx) : (wg & 63);

  { // stage weights into LDS once for all 256 steps (needs cblk)
    const u16x8* s8 = (const u16x8*)(packed + (size_t)cblk * (NCI * 512));
    u16x8* d8 = (u16x8*)lds;
    #pragma unroll
    for (int i = 0; i < 36; ++i) d8[tid + i*256] = s8[tid + i*256];
  }
  __syncthreads();

  const int arow = lane & 15;
  const int kg   = lane >> 4;
  const int b    = rgroup*64 + wave*16 + arow;
  const int crow = rgroup*64 + wave*16 + kg*4;
  const int j    = (cblk << 4) + arow;

  const float*          xrow  = x  + (size_t)b * Tt * Dd;
  const unsigned short* xbrow = xb + (size_t)b * Tt * Dd;

  f32x4 hold = {0.f,0.f,0.f,0.f};

  // prefetch x_0
  bf16x8 xa[16];
  if constexpr (XBF) {
    #pragma unroll
    for (int kk = 0; kk < 16; ++kk) xa[kk] = *(const bf16x8*)(xbrow + kk*32 + kg*8);
  } else {
    #pragma unroll
    for (int kk = 0; kk < 16; ++kk) {
      f32x4 v0 = *(const f32x4*)(xrow + kk*32 + kg*8);
      f32x4 v1 = *(const f32x4*)(xrow + kk*32 + kg*8 + 4);
      bf16x8 a;
      #pragma unroll
      for (int e = 0; e < 4; ++e) { ((unsigned short*)&a)[e] = f2bf(v0[e]); ((unsigned short*)&a)[e+4] = f2bf(v1[e]); }
      xa[kk] = a;
    }
  }

  for (int t = 0; t < Tt; ++t) {
    // ---- wave0: wait for h[t] (R13 hop order; pair-narrowed cross-poll) ----
    if (t > 0 && wave == 0) {
      const unsigned tgt = (unsigned)t;
      if (leader) {
        int cap = 0;
        for (;;) {                     // own XCD members' arrivals
          unsigned v = (lane < members)
              ? rmw_read(&bar[LARR_OFF + (myx*64 + lane)*8]) : tgt;
          if (__all((int)(v >= tgt))) break;
          if (++cap > POLL_CAP) break;
          __builtin_amdgcn_s_sleep(1);
        }
        if (lane == 0) rel_set(&bar[AXC_OFF + myx*8], tgt);   // wbl2 + publish
        cap = 0;
        if (pairmode) {
          for (;;) {                   // partner XCD only
            unsigned v = (lane == 0)
                ? rmw_read(&bar[AXC_OFF + (myx^1)*8]) : tgt;
            if (__all((int)(v >= tgt))) break;
            if (++cap > POLL_CAP) break;
            __builtin_amdgcn_s_sleep(1);
          }
        } else {
          for (;;) {                   // all 8 XCDs (R13 global)
            unsigned v = (lane < 8 && lanecnt > 0)
                ? rmw_read(&bar[AXC_OFF + lane*8]) : tgt;
            if (__all((int)(v >= tgt))) break;
            if (++cap > POLL_CAP) break;
            __builtin_amdgcn_s_sleep(1);
          }
        }
        __builtin_amdgcn_fence(__ATOMIC_ACQUIRE, "agent");    // inv AFTER all wbl2
        if (lane == 0) rmw_set(&bar[RDY_OFF + myx*8], tgt);
      } else {
        int cap = 0;
        while (rmw_read(&bar[RDY_OFF + myx*8]) < tgt && ++cap < POLL_CAP)
          __builtin_amdgcn_s_sleep(1);
      }
    }

    f32x4 az  = {0.f,0.f,0.f,0.f};
    f32x4 arr = {0.f,0.f,0.f,0.f};
    f32x4 axh = {0.f,0.f,0.f,0.f};
    f32x4 ahu = {0.f,0.f,0.f,0.f};

    // ---- x-part MFMAs (waves 1-3 run during wave0's wait) ----
    #pragma unroll
    for (int kk = 0; kk < 16; ++kk) {
      bf16x8 bz = *(const bf16x8*)&lds[(0  + kk)*512 + lane*8];
      bf16x8 br = *(const bf16x8*)&lds[(48 + kk)*512 + lane*8];
      bf16x8 bx = *(const bf16x8*)&lds[(96 + kk)*512 + lane*8];
      az  = __builtin_amdgcn_mfma_f32_16x16x32_bf16(xa[kk], bz, az , 0,0,0);
      arr = __builtin_amdgcn_mfma_f32_16x16x32_bf16(xa[kk], br, arr, 0,0,0);
      axh = __builtin_amdgcn_mfma_f32_16x16x32_bf16(xa[kk], bx, axh, 0,0,0);
    }

    // issue x_{t+1} prefetch (lands in registers; immune to later inv)
    if (t + 1 < Tt) {
      if constexpr (XBF) {
        const unsigned short* xt = xbrow + (size_t)(t+1)*Dd;
        #pragma unroll
        for (int kk = 0; kk < 16; ++kk) xa[kk] = *(const bf16x8*)(xt + kk*32 + kg*8);
      } else {
        const float* xt = xrow + (size_t)(t+1)*Dd;
        #pragma unroll
        for (int kk = 0; kk < 16; ++kk) {
          f32x4 v0 = *(const f32x4*)(xt + kk*32 + kg*8);
          f32x4 v1 = *(const f32x4*)(xt + kk*32 + kg*8 + 4);
          bf16x8 a;
          #pragma unroll
          for (int e = 0; e < 4; ++e) { ((unsigned short*)&a)[e] = f2bf(v0[e]); ((unsigned short*)&a)[e+4] = f2bf(v1[e]); }
          xa[kk] = a;
        }
      }
    }

    if (t > 0) {
      __syncthreads();                 // all waves gated on wave0's wait

      // ---- h loads: plain cached (post-inv L2 miss -> MALL, fresh) ----
      const unsigned short* hrow = hb + (size_t)(t & 1)*(Bb*Hh) + (size_t)b*Hh;
      bf16x8 ha[32];
      #pragma unroll
      for (int kk = 0; kk < 32; ++kk)
        ha[kk] = *(const bf16x8*)(hrow + kk*32 + kg*8);

      // ---- h-part MFMAs ----
      #pragma unroll
      for (int kk = 0; kk < 32; ++kk) {
        bf16x8 bz = *(const bf16x8*)&lds[(16  + kk)*512 + lane*8];
        bf16x8 br = *(const bf16x8*)&lds[(64  + kk)*512 + lane*8];
        bf16x8 bu = *(const bf16x8*)&lds[(112 + kk)*512 + lane*8];
        az  = __builtin_amdgcn_mfma_f32_16x16x32_bf16(ha[kk], bz, az , 0,0,0);
        arr = __builtin_amdgcn_mfma_f32_16x16x32_bf16(ha[kk], br, arr, 0,0,0);
        ahu = __builtin_amdgcn_mfma_f32_16x16x32_bf16(ha[kk], bu, ahu, 0,0,0);
      }
    }

    // ---- gate epilogue ----
    unsigned short hv[4];
    #pragma unroll
    for (int e = 0; e < 4; ++e) {
      float z  = 1.f / (1.f + __expf(-az[e]));
      float r  = 1.f / (1.f + __expf(-arr[e]));
      float u  = axh[e] + ahu[e] * r;
      float hh = 2.f / (1.f + __expf(-2.f * u)) - 1.f;
      float hn = z*hold[e] + (1.f - z)*hh;
      hold[e]  = hn;
      hv[e]    = f2bf(hn);
    }

    if (t < Tt - 1) {
      unsigned short* hbw = hb + (size_t)((t+1) & 1)*(Bb*Hh);
      #pragma unroll
      for (int e = 0; e < 4; ++e) hbw[(size_t)(crow+e)*Hh + j] = hv[e];   // cached
      __syncthreads();               // vmcnt drained: stores are in own-XCD L2
      if (tid == 0)
        rmw_set(&bar[LARR_OFF + (myx*64 + idx)*8], (unsigned)(t + 1));
    } else {
      #pragma unroll
      for (int e = 0; e < 4; ++e) hf[(size_t)(crow+e)*Hh + j] = hold[e];
    }
  }
}

// ---------------- classifier: p = h_last @ W_ph + b_p ----------------
__global__ void classifier(const float* __restrict__ h, const float* __restrict__ Wph,
                           const float* __restrict__ bp, float* __restrict__ out) {
  __shared__ float hsm[8 * Hh];
  const int cb = blockIdx.x, bbk = blockIdx.y;
  const int tid = threadIdx.x;
  const float* h0 = h + (size_t)bbk * 8 * Hh;
  for (int i = tid; i < 8 * Hh; i += 256) {
    int r = i >> 10, k = i & (Hh - 1);
    hsm[k*8 + r] = h0[i];
  }
  __syncthreads();
  int c = cb*256 + tid;
  bool act = c < Cc;
  float acc[8] = {0,0,0,0,0,0,0,0};
  for (int k = 0; k < Hh; ++k) {
    float w = act ? Wph[(size_t)k*Cc + c] : 0.f;
    f32x4 h0v = *(const f32x4*)&hsm[k*8];
    f32x4 h1v = *(const f32x4*)&hsm[k*8 + 4];
    acc[0] += h0v[0]*w; acc[1] += h0v[1]*w; acc[2] += h0v[2]*w; acc[3] += h0v[3]*w;
    acc[4] += h1v[0]*w; acc[5] += h1v[1]*w; acc[6] += h1v[2]*w; acc[7] += h1v[3]*w;
  }
  if (act) {
    float bias = bp[c];
    #pragma unroll
    for (int r = 0; r < 8; ++r) out[(size_t)(bbk*8 + r)*Cc + c] = acc[r] + bias;
  }
}

// ---------------- in-place log_softmax over rows of [256,1000] ----------------
__global__ void logsoftmax(float* __restrict__ out) {
  __shared__ float sm[4];
  float* row = out + (size_t)blockIdx.x * Cc;
  const int tid = threadIdx.x;
  float m = -3.4e38f;
  for (int i = tid; i < Cc; i += 256) m = fmaxf(m, row[i]);
  #pragma unroll
  for (int o = 32; o; o >>= 1) m = fmaxf(m, __shfl_down(m, o, 64));
  if ((tid & 63) == 0) sm[tid >> 6] = m;
  __syncthreads();
  m = fmaxf(fmaxf(sm[0], sm[1]), fmaxf(sm[2], sm[3]));
  __syncthreads();
  float s = 0.f;
  for (int i = tid; i < Cc; i += 256) s += __expf(row[i] - m);
  #pragma unroll
  for (int o = 32; o; o >>= 1) s += __shfl_down(s, o, 64);
  if ((tid & 63) == 0) sm[tid >> 6] = s;
  __syncthreads();
  s = sm[0] + sm[1] + sm[2] + sm[3];
  float lse = m + __logf(s);
  for (int i = tid; i < Cc; i += 256) row[i] -= lse;
}

extern "C" void kernel_launch(void* const* d_in, const int* in_sizes, int n_in,
                              void* d_out, int out_size, void* d_ws, size_t ws_size,
                              hipStream_t stream) {
  (void)in_sizes; (void)n_in; (void)out_size;
  const float* x   = (const float*)d_in[0];
  const float* Wz  = (const float*)d_in[1];
  const float* Wr  = (const float*)d_in[2];
  const float* W   = (const float*)d_in[3];
  const float* Uz  = (const float*)d_in[4];
  const float* Ur  = (const float*)d_in[5];
  const float* U   = (const float*)d_in[6];
  const float* Wph = (const float*)d_in[7];
  const float* bp  = (const float*)d_in[8];
  float* out = (float*)d_out;

  char* ws = (char*)d_ws;
  const size_t OFF_PACK = 0;                       // 9,437,184 B
  const size_t OFF_HF   = 9437184;                 // 1,048,576 B (final h fp32)
  const size_t OFF_HB   = OFF_HF + 1048576;        // 1,048,576 B (2 x bf16 h)
  const size_t OFF_BAR  = OFF_HB + 1048576;        // 32,768 B barrier region
  const size_t OFF_XB   = OFF_BAR + 32768;         // 67,108,864 B (x bf16)
  unsigned short* packed = (unsigned short*)(ws + OFF_PACK);
  float*          hf     = (float*)(ws + OFF_HF);
  unsigned short* hb     = (unsigned short*)(ws + OFF_HB);
  unsigned*       bar    = (unsigned*)(ws + OFF_BAR);
  unsigned short* xbm    = (unsigned short*)(ws + OFF_XB);
  const bool xbf = ws_size >= OFF_XB + (size_t)67108864;

  hipMemsetAsync(bar, 0, BAR_BYTES, stream);       // fresh flags each replay
  pack_weights<<<dim3(2304), dim3(256), 0, stream>>>(Wz, Wr, W, Uz, Ur, U, packed);
  if (xbf) cvt_x<<<dim3(2048), dim3(256), 0, stream>>>(x, xbm);

  void* args[] = { (void*)&x, (void*)&xbm, (void*)&packed, (void*)&hf, (void*)&hb, (void*)&bar };
  if (xbf) {
    hipLaunchCooperativeKernel(reinterpret_cast<void*>(&gru_scan<true>),
                               dim3(256), dim3(256), args, 0, stream);
  } else {
    hipLaunchCooperativeKernel(reinterpret_cast<void*>(&gru_scan<false>),
                               dim3(256), dim3(256), args, 0, stream);
  }

  classifier<<<dim3(4, 32), dim3(256), 0, stream>>>(hf, Wph, bp, out);
  logsoftmax<<<dim3(256), dim3(256), 0, stream>>>(out);
}